// Round 11
// baseline (6912.109 us; speedup 1.0000x reference)
//
#include <hip/hip_runtime.h>

typedef _Float16 half2_t __attribute__((ext_vector_type(2)));
typedef __bf16   bf16x8  __attribute__((ext_vector_type(8)));
typedef float    f32x4   __attribute__((ext_vector_type(4)));
typedef unsigned short u16x8 __attribute__((ext_vector_type(8)));
typedef unsigned int  uint32;
typedef unsigned long long uint64;

#define LSTM_N 32
#define LSTM_T 2048
#define LSTM_D 256
#define LSTM_H 256
#define NG 1024
#define CH 256                    // time-chunk length
#define NCH (LSTM_T / CH)         // 8 chunks
#define MCH (LSTM_N * CH)         // 8192 rows per chunk GEMM

// ---- workspace layout (bytes) ---- (~34.6 MB)
#define OFF_XG   ((size_t)0)
#define SZ_XG    ((size_t)MCH * NG * 4)             // 33,554,432 xg chunk f32
#define OFF_WIHB (OFF_XG + SZ_XG)
#define SZ_WIHB  ((size_t)NG * LSTM_D * 2)          // w_ih bf16
#define OFF_BIAS (OFF_WIHB + SZ_WIHB)
#define SZ_BIAS  ((size_t)4096)
#define OFF_WPK  (OFF_BIAS + SZ_BIAS)
#define SZ_WPK   ((size_t)1024 * 128 * 4)           // 524,288 w_hh f16 pairs (row-per-thread)
#define OFF_CST  (OFF_WPK + SZ_WPK)
#define SZ_CST   ((size_t)LSTM_N * 256 * 4)         // c state f32
#define OFF_HST  (OFF_CST + SZ_CST)
#define SZ_HST   ((size_t)LSTM_N * 128 * 4)         // h state f16-pairs (u32)

#if defined(__has_builtin)
#if __has_builtin(__builtin_amdgcn_fdot2)
#define HAVE_FDOT2 1
#endif
#endif

// PROVEN datapath (R2/R3/R6/R8/R9, absmax 0.0078). Inline-asm v_dot2 is
// numerically WRONG on gfx950 (R5/R7 failed identically) - permanently banned.
__device__ __forceinline__ float fdot2(uint32 w, uint32 h, float acc) {
#ifdef HAVE_FDOT2
  return __builtin_amdgcn_fdot2(__builtin_bit_cast(half2_t, w),
                                __builtin_bit_cast(half2_t, h), acc, false);
#else
  half2_t wv = __builtin_bit_cast(half2_t, w);
  half2_t hv = __builtin_bit_cast(half2_t, h);
  float r = fmaf((float)wv.x, (float)hv.x, acc);
  return fmaf((float)wv.y, (float)hv.y, r);
#endif
}

__device__ __forceinline__ float sigm(float x) { return 1.f / (1.f + __expf(-x)); }
__device__ __forceinline__ float tanh_fast(float x) { return 2.f / (1.f + __expf(-2.f * x)) - 1.f; }

__device__ __forceinline__ unsigned short f2bf(float f) {
  uint32 u = __builtin_bit_cast(uint32, f);
  uint32 r = (u + 0x7FFFu + ((u >> 16) & 1u)) >> 16;
  return (unsigned short)r;
}

// ---------------- kernels ----------------

__global__ void cvt_bf16_k(const float* __restrict__ src, unsigned short* __restrict__ dst, int n) {
  int i = blockIdx.x * blockDim.x + threadIdx.x;
  if (4 * i + 3 < n) {
    float4 v = ((const float4*)src)[i];
    ushort4 o;
    o.x = f2bf(v.x); o.y = f2bf(v.y); o.z = f2bf(v.z); o.w = f2bf(v.w);
    ((ushort4*)dst)[i] = o;
  }
}

__global__ void bias_sum_k(const float* __restrict__ bih, const float* __restrict__ bhh,
                           float* __restrict__ bias) {
  int g = blockIdx.x * blockDim.x + threadIdx.x;
  if (g < NG) bias[g] = bih[g] + bhh[g];
}

// Pack w_hh f32[1024][256] -> row-per-thread f16-pair images.
// Scan thread t owns row t: wr[j] = pair (k=2j, 2j+1), j=0..127.
// Stored as wpk[((j>>2)*1024 + r)*4 + (j&3)] so scan's uint4 load
// wpk4[ig*1024 + t] is fully coalesced over t.
__global__ void wpack_k(const float* __restrict__ whh, uint32* __restrict__ wpk) {
  int e = blockIdx.x * blockDim.x + threadIdx.x;  // < 131072
  int j = e >> 10;          // k-pair 0..127
  int r = e & 1023;         // row
  half2_t h;
  h.x = (_Float16)whh[r * 256 + 2 * j];
  h.y = (_Float16)whh[r * 256 + 2 * j + 1];
  wpk[((size_t)(j >> 2) * 1024 + r) * 4 + (j & 3)] = __builtin_bit_cast(uint32, h);
}

// init carried state (every launch -> replay-safe)
__global__ void state_init_k(const float* __restrict__ state, float* __restrict__ cst,
                             uint32* __restrict__ hst) {
  int i = blockIdx.x * blockDim.x + threadIdx.x;  // < 8192
  int n = i >> 8, j = i & 255;
  cst[i] = state[n * 512 + 256 + j];
  if ((j & 1) == 0) {
    half2_t h2;
    h2.x = (_Float16)state[n * 512 + j];
    h2.y = (_Float16)state[n * 512 + j + 1];
    hst[(n << 7) + (j >> 1)] = __builtin_bit_cast(uint32, h2);
  }
}

// xg[8192][1024] = x(chunk rows, cvt bf16 inline) @ w_ih_bf16^T + bias  [R2/R3 verbatim]
__global__ __launch_bounds__(256) void gemm_xg(const float* __restrict__ x,
                                               const unsigned short* __restrict__ wb,
                                               const float* __restrict__ bias,
                                               float* __restrict__ xg, int ch) {
  __shared__ unsigned short As[128 * 40];  // 80B rows (stride = 5*16B, odd*16)
  __shared__ unsigned short Bs[128 * 40];
  const int tid = threadIdx.x;
  const int m0 = blockIdx.y * 128;
  const int g0 = blockIdx.x * 128;
  const int w = tid >> 6;
  const int lane = tid & 63;
  const int wm = (w >> 1) * 64, wn = (w & 1) * 64;
  const int row_l = tid >> 2;  // 0..63
  const int q = tid & 3;
  const int lr = lane & 15, kg = lane >> 4;

  size_t grow[2];
#pragma unroll
  for (int r = 0; r < 2; ++r) {
    int gm = m0 + row_l + 64 * r;
    grow[r] = (size_t)(gm >> 8) * LSTM_T + (size_t)ch * CH + (gm & 255);
  }

  f32x4 acc[4][4];
#pragma unroll
  for (int i = 0; i < 4; ++i)
#pragma unroll
    for (int j = 0; j < 4; ++j) acc[i][j] = (f32x4){0.f, 0.f, 0.f, 0.f};

  for (int kt = 0; kt < 8; ++kt) {
#pragma unroll
    for (int r = 0; r < 2; ++r) {
      int row = row_l + 64 * r;
      const float* ap = x + grow[r] * 256 + kt * 32 + q * 8;
      float4 v0 = *(const float4*)ap;
      float4 v1 = *(const float4*)(ap + 4);
      u16x8 o;
      o[0] = f2bf(v0.x); o[1] = f2bf(v0.y); o[2] = f2bf(v0.z); o[3] = f2bf(v0.w);
      o[4] = f2bf(v1.x); o[5] = f2bf(v1.y); o[6] = f2bf(v1.z); o[7] = f2bf(v1.w);
      *(uint4*)((char*)As + row * 80 + q * 16) = __builtin_bit_cast(uint4, o);
      uint4 bv = *(const uint4*)(wb + (size_t)(g0 + row) * 256 + kt * 32 + q * 8);
      *(uint4*)((char*)Bs + row * 80 + q * 16) = bv;
    }
    __syncthreads();
    bf16x8 af[4], bfr[4];
#pragma unroll
    for (int i = 0; i < 4; ++i)
      af[i] = __builtin_bit_cast(bf16x8, *(const uint4*)((char*)As + (wm + 16 * i + lr) * 80 + kg * 16));
#pragma unroll
    for (int j = 0; j < 4; ++j)
      bfr[j] = __builtin_bit_cast(bf16x8, *(const uint4*)((char*)Bs + (wn + 16 * j + lr) * 80 + kg * 16));
#pragma unroll
    for (int i = 0; i < 4; ++i)
#pragma unroll
      for (int j = 0; j < 4; ++j)
        acc[i][j] = __builtin_amdgcn_mfma_f32_16x16x32_bf16(af[i], bfr[j], acc[i][j], 0, 0, 0);
    __syncthreads();
  }
#pragma unroll
  for (int j = 0; j < 4; ++j) {
    int gc = g0 + wn + 16 * j + lr;
    float bj = bias[gc];
#pragma unroll
    for (int i = 0; i < 4; ++i) {
#pragma unroll
      for (int r = 0; r < 4; ++r) {
        int m = m0 + wm + 16 * i + kg * 4 + r;
        xg[(size_t)m * NG + gc] = acc[i][j][r] + bj;
      }
    }
  }
}

// Recurrent scan: 32 WGs (1 sample/CU), 1024 threads (16 waves), NO cross-WG
// exchange. Thread t owns gate-row t entirely (128 f16-pair weights = full
// k=256). h (512B) broadcast from LDS; gates via actb (R3/R6-proven path);
// cell by t<256. 2 barriers/step; only in-loop global ops = 4B xg prefetch
// + 16-step-batched output flush.
__global__ __launch_bounds__(1024, 1) void lstm_scan(const float* __restrict__ xg,
                                                     const uint4* __restrict__ wpk4,
                                                     float* __restrict__ cst,
                                                     uint32* __restrict__ hst,
                                                     float* __restrict__ out, int ch) {
  __shared__ uint32 hbuf[128];        // full h as f16 pairs
  __shared__ float actb[1024];
  __shared__ float ostage[16][256];   // h staging, flushed every 16 steps

  const int n = blockIdx.x;
  const int t = threadIdx.x;          // global gate row
  const int q = t >> 8;               // gate: 0=i 1=f 2=g 3=o (wave-uniform)

  // weights -> 128 regs (AGPR split accepted; builtin fdot2 pays the copy)
  uint32 wr[128];
#pragma unroll
  for (int ig = 0; ig < 32; ++ig) {
    uint4 v = wpk4[(size_t)ig * 1024 + t];
    wr[4 * ig + 0] = v.x; wr[4 * ig + 1] = v.y; wr[4 * ig + 2] = v.z; wr[4 * ig + 3] = v.w;
  }
  float c = 0.f;
  if (t < 256) c = cst[n * 256 + t];
  if (t < 128) hbuf[t] = hst[n * 128 + t];
  __syncthreads();

  const float* xgn = xg + (size_t)n * CH * NG;
  float* outb = out + ((size_t)n * LSTM_T + (size_t)ch * CH) * LSTM_H;

  float xcur = xgn[t];

  for (int tt = 0; tt < CH; ++tt) {
    float xnext = (tt < CH - 1) ? xgn[(size_t)(tt + 1) * NG + t] : 0.f;
    // full-row dot: 128 fdot2, two independent chains for ILP.
    // All lanes read the same hbuf addresses -> LDS broadcast, conflict-free.
    float a0 = 0.f, a1 = 0.f;
    const uint4* hb4 = (const uint4*)hbuf;
#pragma unroll
    for (int blk = 0; blk < 16; ++blk) {
      uint32 hh[8];
      *(uint4*)&hh[0] = hb4[2 * blk];
      *(uint4*)&hh[4] = hb4[2 * blk + 1];
      a0 = fdot2(wr[8 * blk + 0], hh[0], a0);
      a0 = fdot2(wr[8 * blk + 1], hh[1], a0);
      a0 = fdot2(wr[8 * blk + 2], hh[2], a0);
      a0 = fdot2(wr[8 * blk + 3], hh[3], a0);
      a1 = fdot2(wr[8 * blk + 4], hh[4], a1);
      a1 = fdot2(wr[8 * blk + 5], hh[5], a1);
      a1 = fdot2(wr[8 * blk + 6], hh[6], a1);
      a1 = fdot2(wr[8 * blk + 7], hh[7], a1);
    }
    float pre = a0 + a1 + xcur;
    xcur = xnext;
    float a = (q == 2) ? tanh_fast(pre) : sigm(pre);
    actb[t] = a;
    __syncthreads();                  // BAR-A: gates ready
    if (t < 256) {                    // cell update: unit t
      float gi = actb[t];
      float gf = actb[256 + t];
      float gg = actb[512 + t];
      float go = actb[768 + t];
      c = gf * c + gi * gg;
      float h = go * tanh_fast(c);
      _Float16 hf = (_Float16)h;
      ((unsigned short*)hbuf)[t] = __builtin_bit_cast(unsigned short, hf);
      ostage[tt & 15][t] = h;
      if (ch == NCH - 1 && tt == CH - 1) {
        float* os = out + (size_t)LSTM_N * LSTM_T * LSTM_H + n * 512;
        os[t] = h;
        os[256 + t] = c;
      }
    }
    __syncthreads();                  // BAR-B: hbuf/ostage visible
    if ((tt & 15) == 15) {            // flush 16 staged steps, coalesced
      int sl = t >> 6, c4 = t & 63;
      float4 v = *(const float4*)&ostage[sl][4 * c4];
      *(float4*)&outb[(size_t)(tt - 15 + sl) * LSTM_H + 4 * c4] = v;
    }
  }
  // persist carried state for next chunk
  if (t < 256) cst[n * 256 + t] = c;
  if (t < 128) hst[n * 128 + t] = hbuf[t];
}

extern "C" void kernel_launch(void* const* d_in, const int* in_sizes, int n_in,
                              void* d_out, int out_size, void* d_ws, size_t ws_size,
                              hipStream_t stream) {
  const float* x   = (const float*)d_in[0];
  const float* st  = (const float*)d_in[1];
  const float* wih = (const float*)d_in[2];
  const float* whh = (const float*)d_in[3];
  const float* bih = (const float*)d_in[4];
  const float* bhh = (const float*)d_in[5];
  float* out = (float*)d_out;
  char* ws = (char*)d_ws;

  float* xg = (float*)(ws + OFF_XG);
  unsigned short* wihb = (unsigned short*)(ws + OFF_WIHB);
  float* bias = (float*)(ws + OFF_BIAS);
  uint32* wpk = (uint32*)(ws + OFF_WPK);
  float* cst = (float*)(ws + OFF_CST);
  uint32* hst = (uint32*)(ws + OFF_HST);

  cvt_bf16_k<<<(NG * LSTM_D / 4 + 255) / 256, 256, 0, stream>>>(wih, wihb, NG * LSTM_D);
  bias_sum_k<<<4, 256, 0, stream>>>(bih, bhh, bias);
  wpack_k<<<512, 256, 0, stream>>>(whh, wpk);
  state_init_k<<<32, 256, 0, stream>>>(st, cst, hst);

  for (int ch = 0; ch < NCH; ++ch) {
    gemm_xg<<<dim3(NG / 128, MCH / 128), 256, 0, stream>>>(x, wihb, bias, xg, ch);
    lstm_scan<<<32, 1024, 0, stream>>>(xg, (const uint4*)wpk, cst, hst, out, ch);
  }
}

// Round 12
// 3288.565 us; speedup vs baseline: 2.1019x; 2.1019x over previous
//
#include <hip/hip_runtime.h>

typedef _Float16 half2_t __attribute__((ext_vector_type(2)));
typedef __bf16   bf16x8  __attribute__((ext_vector_type(8)));
typedef float    f32x4   __attribute__((ext_vector_type(4)));
typedef unsigned short u16x8 __attribute__((ext_vector_type(8)));
typedef unsigned int  uint32;
typedef unsigned long long uint64;

#define LSTM_N 32
#define LSTM_T 2048
#define LSTM_D 256
#define LSTM_H 256
#define NG 1024
#define CH 256                    // time-chunk length
#define NCH (LSTM_T / CH)         // 8 chunks
#define MCH (LSTM_N * CH)         // 8192 rows per chunk GEMM

// ---- workspace layout (bytes) ---- (~34.6 MB)
#define OFF_XG   ((size_t)0)
#define SZ_XG    ((size_t)MCH * NG * 4)             // 33,554,432 xg chunk f32
#define OFF_WIHB (OFF_XG + SZ_XG)
#define SZ_WIHB  ((size_t)NG * LSTM_D * 2)          // w_ih bf16
#define OFF_BIAS (OFF_WIHB + SZ_WIHB)
#define SZ_BIAS  ((size_t)4096)
#define OFF_WPK  (OFF_BIAS + SZ_BIAS)
#define SZ_WPK   ((size_t)4 * 512 * 64 * 4)         // 524,288 w_hh f16 pairs (quarter/thread)
#define OFF_CST  (OFF_WPK + SZ_WPK)
#define SZ_CST   ((size_t)LSTM_N * 256 * 4)         // c state f32
#define OFF_HX   (OFF_CST + SZ_CST)
#define SZ_HX    ((size_t)LSTM_N * 2 * 128 * 8)     // 65,536 board: tagged-u64 unit-pair slots

#if defined(__has_builtin)
#if __has_builtin(__builtin_amdgcn_fdot2)
#define HAVE_FDOT2 1
#endif
#endif

// PROVEN datapath (R2/R3/R6/R8/R9, absmax 0.0078). Inline-asm v_dot2 is
// numerically WRONG on gfx950 (R5/R7 failed identically) - permanently banned.
__device__ __forceinline__ float fdot2(uint32 w, uint32 h, float acc) {
#ifdef HAVE_FDOT2
  return __builtin_amdgcn_fdot2(__builtin_bit_cast(half2_t, w),
                                __builtin_bit_cast(half2_t, h), acc, false);
#else
  half2_t wv = __builtin_bit_cast(half2_t, w);
  half2_t hv = __builtin_bit_cast(half2_t, h);
  float r = fmaf((float)wv.x, (float)hv.x, acc);
  return fmaf((float)wv.y, (float)hv.y, r);
#endif
}

__device__ __forceinline__ float sigm(float x) { return 1.f / (1.f + __expf(-x)); }
__device__ __forceinline__ float tanh_fast(float x) { return 2.f / (1.f + __expf(-2.f * x)) - 1.f; }

__device__ __forceinline__ unsigned short f2bf(float f) {
  uint32 u = __builtin_bit_cast(uint32, f);
  uint32 r = (u + 0x7FFFu + ((u >> 16) & 1u)) >> 16;
  return (unsigned short)r;
}

// reduce-scatter over 8 lanes (bits 0-2 of lane id): lane kap gets sum of a[kap].
// Compile-time register indices only (rule #20). Proven R2/R3/R6/R9.
__device__ __forceinline__ float bfly8(const float a[8], int kap) {
  float k0[4], g0[4];
  const bool b4 = (kap & 4) != 0;
#pragma unroll
  for (int v = 0; v < 4; ++v) {
    k0[v] = b4 ? a[v + 4] : a[v];
    g0[v] = b4 ? a[v] : a[v + 4];
  }
#pragma unroll
  for (int v = 0; v < 4; ++v) k0[v] += __shfl_xor(g0[v], 4, 64);
  float k1[2], g1[2];
  const bool b2 = (kap & 2) != 0;
#pragma unroll
  for (int v = 0; v < 2; ++v) {
    k1[v] = b2 ? k0[v + 2] : k0[v];
    g1[v] = b2 ? k0[v] : k0[v + 2];
  }
#pragma unroll
  for (int v = 0; v < 2; ++v) k1[v] += __shfl_xor(g1[v], 2, 64);
  const bool b1 = (kap & 1) != 0;
  float k2 = b1 ? k1[1] : k1[0];
  float g2 = b1 ? k1[0] : k1[1];
  return k2 + __shfl_xor(g2, 1, 64);
}

// ---------------- kernels ----------------

__global__ void cvt_bf16_k(const float* __restrict__ src, unsigned short* __restrict__ dst, int n) {
  int i = blockIdx.x * blockDim.x + threadIdx.x;
  if (4 * i + 3 < n) {
    float4 v = ((const float4*)src)[i];
    ushort4 o;
    o.x = f2bf(v.x); o.y = f2bf(v.y); o.z = f2bf(v.z); o.w = f2bf(v.w);
    ((ushort4*)dst)[i] = o;
  }
}

__global__ void bias_sum_k(const float* __restrict__ bih, const float* __restrict__ bhh,
                           float* __restrict__ bias) {
  int g = blockIdx.x * blockDim.x + threadIdx.x;
  if (g < NG) bias[g] = bih[g] + bhh[g];
}

// Pack w_hh f32[1024][256] -> quarter-split f16-pair images.
// Scan WG j (units [64j,64j+64) x 4 gates = 256 rows, full k), thread t:
// kap=t&15 (k in [16kap,16kap+16)), rg=t>>4 (rows rho=8rg..8rg+8).
// wr[i]: rho = 8rg + (i>>3), global row R = (rho>>6)*256 + 64j + (rho&63),
//        k = 16kap + 2(i&7). Load wpk4[(j*16+ig)*512+t] coalesced.
__global__ void wpack_k(const float* __restrict__ whh, uint32* __restrict__ wpk) {
  int e = blockIdx.x * blockDim.x + threadIdx.x;  // < 131072
  int j = e >> 15;
  int rem = e & 32767;
  int i = rem >> 9;        // 0..63
  int t = rem & 511;
  int kap = t & 15, rg = t >> 4;
  int rho = 8 * rg + (i >> 3);
  int R = (rho >> 6) * 256 + 64 * j + (rho & 63);
  int k = 16 * kap + 2 * (i & 7);
  half2_t h;
  h.x = (_Float16)whh[R * 256 + k];
  h.y = (_Float16)whh[R * 256 + k + 1];
  wpk[((j * 16 + (i >> 2)) * 512 + t) * 4 + (i & 3)] = __builtin_bit_cast(uint32, h);
}

// init carried state + board (every launch -> replay-safe).
// Board per sample: [parity 2][128 unit-pair slots] tagged u64.
// parity0 pre-posted with h0 + tag 0 (step-0 want); parity1 = never-match tag.
__global__ void state_init_k(const float* __restrict__ state, float* __restrict__ cst,
                             uint64* __restrict__ hx) {
  int i = blockIdx.x * blockDim.x + threadIdx.x;  // < 8192
  int n = i >> 8, jj = i & 255;
  cst[i] = state[n * 512 + 256 + jj];
  if (jj < 128) {  // parity0 slot jj: units (2jj, 2jj+1)
    half2_t h2;
    h2.x = (_Float16)state[n * 512 + 2 * jj];
    h2.y = (_Float16)state[n * 512 + 2 * jj + 1];
    hx[(size_t)n * 256 + jj] = (uint64)__builtin_bit_cast(uint32, h2);  // tag 0
  } else {
    hx[(size_t)n * 256 + jj] = 0x8000000000000000ull;  // parity1: never matches
  }
}

// xg[8192][1024] = x(chunk rows, cvt bf16 inline) @ w_ih_bf16^T + bias  [R2/R3 verbatim]
__global__ __launch_bounds__(256) void gemm_xg(const float* __restrict__ x,
                                               const unsigned short* __restrict__ wb,
                                               const float* __restrict__ bias,
                                               float* __restrict__ xg, int ch) {
  __shared__ unsigned short As[128 * 40];  // 80B rows (stride = 5*16B, odd*16)
  __shared__ unsigned short Bs[128 * 40];
  const int tid = threadIdx.x;
  const int m0 = blockIdx.y * 128;
  const int g0 = blockIdx.x * 128;
  const int w = tid >> 6;
  const int lane = tid & 63;
  const int wm = (w >> 1) * 64, wn = (w & 1) * 64;
  const int row_l = tid >> 2;  // 0..63
  const int q = tid & 3;
  const int lr = lane & 15, kg = lane >> 4;

  size_t grow[2];
#pragma unroll
  for (int r = 0; r < 2; ++r) {
    int gm = m0 + row_l + 64 * r;
    grow[r] = (size_t)(gm >> 8) * LSTM_T + (size_t)ch * CH + (gm & 255);
  }

  f32x4 acc[4][4];
#pragma unroll
  for (int i = 0; i < 4; ++i)
#pragma unroll
    for (int j = 0; j < 4; ++j) acc[i][j] = (f32x4){0.f, 0.f, 0.f, 0.f};

  for (int kt = 0; kt < 8; ++kt) {
#pragma unroll
    for (int r = 0; r < 2; ++r) {
      int row = row_l + 64 * r;
      const float* ap = x + grow[r] * 256 + kt * 32 + q * 8;
      float4 v0 = *(const float4*)ap;
      float4 v1 = *(const float4*)(ap + 4);
      u16x8 o;
      o[0] = f2bf(v0.x); o[1] = f2bf(v0.y); o[2] = f2bf(v0.z); o[3] = f2bf(v0.w);
      o[4] = f2bf(v1.x); o[5] = f2bf(v1.y); o[6] = f2bf(v1.z); o[7] = f2bf(v1.w);
      *(uint4*)((char*)As + row * 80 + q * 16) = __builtin_bit_cast(uint4, o);
      uint4 bv = *(const uint4*)(wb + (size_t)(g0 + row) * 256 + kt * 32 + q * 8);
      *(uint4*)((char*)Bs + row * 80 + q * 16) = bv;
    }
    __syncthreads();
    bf16x8 af[4], bfr[4];
#pragma unroll
    for (int i = 0; i < 4; ++i)
      af[i] = __builtin_bit_cast(bf16x8, *(const uint4*)((char*)As + (wm + 16 * i + lr) * 80 + kg * 16));
#pragma unroll
    for (int j = 0; j < 4; ++j)
      bfr[j] = __builtin_bit_cast(bf16x8, *(const uint4*)((char*)Bs + (wn + 16 * j + lr) * 80 + kg * 16));
#pragma unroll
    for (int i = 0; i < 4; ++i)
#pragma unroll
      for (int j = 0; j < 4; ++j)
        acc[i][j] = __builtin_amdgcn_mfma_f32_16x16x32_bf16(af[i], bfr[j], acc[i][j], 0, 0, 0);
    __syncthreads();
  }
#pragma unroll
  for (int j = 0; j < 4; ++j) {
    int gc = g0 + wn + 16 * j + lr;
    float bj = bias[gc];
#pragma unroll
    for (int i = 0; i < 4; ++i) {
#pragma unroll
      for (int r = 0; r < 4; ++r) {
        int m = m0 + wm + 16 * i + kg * 4 + r;
        xg[(size_t)m * NG + gc] = acc[i][j][r] + bj;
      }
    }
  }
}

// Recurrent scan: 128 WGs = 32 samples x 4 quarters (b: n=b&31, j=b>>5 ->
// all 4 quarters of a sample share an XCD under round-robin; correctness is
// placement-independent). WG j: units [64j,64j+64) x 4 gates, full k=256.
// Thread: kap=t&15 k-slice (16 h values = 2 LDS reads - the R11 lesson),
// rg=t>>4 rows 8rg..8rg+8; 64 fdot2; shfl_xor(8) + bfly8 reduce; gates via
// actb; cell by t<64. Exchange: tagged-u64 board; posts land ~3/4 step before
// the consumer spin -> first poll succeeds in steady state (latency off-chain).
__global__ __launch_bounds__(512, 1) void lstm_scan(const float* __restrict__ xg,
                                                    const uint4* __restrict__ wpk4,
                                                    float* __restrict__ cst,
                                                    uint64* __restrict__ hx,
                                                    float* __restrict__ out, int ch) {
  __shared__ uint32 hb[2][128];       // full h board copy (u32 = unit pair), parity
  __shared__ float actb[256];         // this WG's 256 gate rows
  __shared__ float ostage[16][64];    // h staging, flushed every 16 steps

  const int b = blockIdx.x;
  const int n = b & 31;
  const int j = b >> 5;               // quarter 0..3
  const int t = threadIdx.x;
  const int kap = t & 15;
  const int rg = t >> 4;              // 0..31
  const int rho_f = 8 * rg + (t & 7); // row this lane finalizes after reduce
  const int qf = rho_f >> 6;          // its gate
  const int Rf = qf * 256 + 64 * j + (rho_f & 63);  // its global gate-row

  // weights -> 64 regs (AGPR split accepted; builtin fdot2 pays the copy)
  uint32 wr[64];
#pragma unroll
  for (int ig = 0; ig < 16; ++ig) {
    uint4 v = wpk4[(j * 16 + ig) * 512 + t];
    wr[4 * ig + 0] = v.x; wr[4 * ig + 1] = v.y; wr[4 * ig + 2] = v.z; wr[4 * ig + 3] = v.w;
  }
  float c = 0.f;
  if (t < 64) c = cst[n * 256 + 64 * j + t];

  const float* xgn = xg + (size_t)n * CH * NG;
  float* outb = out + ((size_t)n * LSTM_T + (size_t)ch * CH) * LSTM_H;
  uint64* board = hx + (size_t)n * 256;   // [parity][128 slots]
  const int gsbase = ch * CH;

  float xcur = xgn[Rf];

  for (int tt = 0; tt < CH; ++tt) {
    const int s = gsbase + tt;          // global step
    const int par = s & 1;
    // deposit board slots (all 128 at chunk start; non-own quarters after)
    if (t < 128 && (tt == 0 || (t >> 5) != j)) {
      uint64* sp = &board[(size_t)par * 128 + t];
      uint64 v;
      for (;;) {
        v = __hip_atomic_load(sp, __ATOMIC_RELAXED, __HIP_MEMORY_SCOPE_AGENT);
        if ((uint32)(v >> 32) == (uint32)s) break;
        __builtin_amdgcn_s_sleep(1);
      }
      hb[par][t] = (uint32)v;
    }
    __syncthreads();                    // BAR-A: board complete
    // dots over this lane's 16-k slice (2 LDS b128 reads)
    uint32 hh[8];
    *(uint4*)&hh[0] = *(const uint4*)&hb[par][8 * kap];
    *(uint4*)&hh[4] = *(const uint4*)&hb[par][8 * kap + 4];
    float acc[8];
#pragma unroll
    for (int r = 0; r < 8; ++r) {
      float a = 0.f;
#pragma unroll
      for (int m = 0; m < 8; ++m) a = fdot2(wr[r * 8 + m], hh[m], a);
      acc[r] = a;
    }
    // reduce over 16 k-lanes: full-sum across bit 3, then bfly8 (bits 0-2)
#pragma unroll
    for (int r = 0; r < 8; ++r) acc[r] += __shfl_xor(acc[r], 8, 64);
    float ssum = bfly8(acc, t & 7);
    float pre = ssum + xcur;
    if (tt < CH - 1) xcur = xgn[(size_t)(tt + 1) * NG + Rf];
    float a = (qf == 2) ? tanh_fast(pre) : sigm(pre);
    if (kap < 8) actb[rho_f] = a;       // kap>=8 lanes are duplicates
    __syncthreads();                    // BAR-B: actb ready
    if (t < 64) {                       // cell: unit 64j+t
      float gi = actb[t];
      float gf = actb[64 + t];
      float gg = actb[128 + t];
      float go = actb[192 + t];
      c = gf * c + gi * gg;
      float h = go * tanh_fast(c);
      _Float16 hf = (_Float16)h;
      uint32 hz = (uint32)__builtin_bit_cast(unsigned short, hf);
      // own units into next-parity LDS board
      ((unsigned short*)&hb[par ^ 1][0])[64 * j + t] = (unsigned short)hz;
      ostage[tt & 15][t] = h;
      uint32 hn = (uint32)__shfl_xor((int)hz, 1, 64);
      if ((t & 1) == 0) {               // post pair, tag s+1 (always, x-chunk too)
        uint64 msg = (uint64)(hz | (hn << 16)) | ((uint64)(uint32)(s + 1) << 32);
        __hip_atomic_store(&board[(size_t)((s + 1) & 1) * 128 + 32 * j + (t >> 1)],
                           msg, __ATOMIC_RELAXED, __HIP_MEMORY_SCOPE_AGENT);
      }
      if (ch == NCH - 1 && tt == CH - 1) {
        float* os = out + (size_t)LSTM_N * LSTM_T * LSTM_H + n * 512;
        os[64 * j + t] = h;
        os[256 + 64 * j + t] = c;
      }
    }
    if ((tt & 15) == 15) {              // flush 16 staged steps (uniform branch)
      __syncthreads();
      if (t < 256) {
        int sl = t >> 4, c4 = t & 15;
        float4 v = *(const float4*)&ostage[sl][4 * c4];
        *(float4*)&outb[(size_t)(tt - 15 + sl) * LSTM_H + 64 * j + 4 * c4] = v;
      }
    }
  }
  // persist c (h carries over via the board posts)
  if (t < 64) cst[n * 256 + 64 * j + t] = c;
}

extern "C" void kernel_launch(void* const* d_in, const int* in_sizes, int n_in,
                              void* d_out, int out_size, void* d_ws, size_t ws_size,
                              hipStream_t stream) {
  const float* x   = (const float*)d_in[0];
  const float* st  = (const float*)d_in[1];
  const float* wih = (const float*)d_in[2];
  const float* whh = (const float*)d_in[3];
  const float* bih = (const float*)d_in[4];
  const float* bhh = (const float*)d_in[5];
  float* out = (float*)d_out;
  char* ws = (char*)d_ws;

  float* xg = (float*)(ws + OFF_XG);
  unsigned short* wihb = (unsigned short*)(ws + OFF_WIHB);
  float* bias = (float*)(ws + OFF_BIAS);
  uint32* wpk = (uint32*)(ws + OFF_WPK);
  float* cst = (float*)(ws + OFF_CST);
  uint64* hx = (uint64*)(ws + OFF_HX);

  cvt_bf16_k<<<(NG * LSTM_D / 4 + 255) / 256, 256, 0, stream>>>(wih, wihb, NG * LSTM_D);
  bias_sum_k<<<4, 256, 0, stream>>>(bih, bhh, bias);
  wpack_k<<<512, 256, 0, stream>>>(whh, wpk);
  state_init_k<<<32, 256, 0, stream>>>(st, cst, hx);

  for (int ch = 0; ch < NCH; ++ch) {
    gemm_xg<<<dim3(NG / 128, MCH / 128), 256, 0, stream>>>(x, wihb, bias, xg, ch);
    lstm_scan<<<128, 512, 0, stream>>>(xg, (const uint4*)wpk, cst, hx, out, ch);
  }
}